// Round 12
// baseline (5189.435 us; speedup 1.0000x reference)
//
#include <hip/hip_runtime.h>
#include <math.h>

// Persistent-kernel NTM, R12: shorten per-phase critical paths.
// - s_xg: x-part of LSTM gates (16 rows x 128 t) precomputed at INIT in LDS.
// - W_hh*h(t) computed in phase F by idle waves 2-3 (s_co persists from C);
//   phase A = tiny rvec-GEMV + elementwise only.
// - scal prefetched to LDS in D (wave 7); read-key norm computed in F (wave 4).
// - pub barriers: 2 alternating arrays, 1 cacheline per word; no drains except
//   A/C (bulk stores) and J (atomics). Boundary values self-tagged u64.

#define NBLK 128
#define NTHR 512
#define Msz  16384
#define Dsz  256
#define Hsz  512
#define Isz  256
#define Tlen 128
#define RPB  128
#define NG   16
#define PUBSTR 16  // u64 stride (128B line)

struct Params { const float* in[34]; float* out; float* ws; };

__device__ __forceinline__ float wred64(float v){
#pragma unroll
  for (int o = 32; o > 0; o >>= 1) v += __shfl_xor(v, o, 64);
  return v;
}
__device__ __forceinline__ float wred32(float v){
#pragma unroll
  for (int o = 16; o > 0; o >>= 1) v += __shfl_xor(v, o, 32);
  return v;
}
__device__ __forceinline__ float sigm(float x){ return 1.f / (1.f + __expf(-x)); }
__device__ __forceinline__ float softplusf(float x){ return (x > 20.f) ? x : log1pf(__expf(x)); }

__device__ __forceinline__ void gstore(float* p, float v){
  __hip_atomic_store(p, v, __ATOMIC_RELAXED, __HIP_MEMORY_SCOPE_AGENT);
}
__device__ __forceinline__ float gload(const float* p){
  return __hip_atomic_load(p, __ATOMIC_RELAXED, __HIP_MEMORY_SCOPE_AGENT);
}
__device__ __forceinline__ void gstore64(unsigned long long* p, unsigned long long v){
  __hip_atomic_store(p, v, __ATOMIC_RELAXED, __HIP_MEMORY_SCOPE_AGENT);
}
__device__ __forceinline__ unsigned long long gload64(const unsigned long long* p){
  return __hip_atomic_load(p, __ATOMIC_RELAXED, __HIP_MEMORY_SCOPE_AGENT);
}
// lgkmcnt(0)-only barrier (no vmcnt drain)
__device__ __forceinline__ void lbar(){
  __builtin_amdgcn_s_waitcnt(0xC07F);
  __builtin_amdgcn_s_barrier();
}

__global__ void __launch_bounds__(NTHR, 1)
ntm_kernel(Params P)
{
  const int b   = blockIdx.x;
  const int tid = threadIdx.x;
  const int wv  = tid >> 6;   // wave 0..7
  const int ln  = tid & 63;

  // ------- inputs -------
  const float* inputs  = P.in[0];
  const float* mem0    = P.in[1];
  const float* read_w0 = P.in[2];
  const float* write_w0= P.in[3];
  const float* W_ih = P.in[4];
  const float* W_hh = P.in[5];
  const float* b_ih = P.in[6];
  const float* b_hh = P.in[7];
  const float* Wo   = P.in[8];
  const float* bo   = P.in[9];
  const float* r_Wk = P.in[10]; const float* r_bk = P.in[11];
  const float* r_Wb = P.in[12]; const float* r_bb = P.in[13];
  const float* r_Wg = P.in[14]; const float* r_bg = P.in[15];
  const float* r_Ws = P.in[16]; const float* r_bs = P.in[17];
  const float* r_Wp = P.in[18]; const float* r_bp = P.in[19];
  const float* w_Wk = P.in[20]; const float* w_bk = P.in[21];
  const float* w_Wb = P.in[22]; const float* w_bb = P.in[23];
  const float* w_Wg = P.in[24]; const float* w_bg = P.in[25];
  const float* w_Ws = P.in[26]; const float* w_bs = P.in[27];
  const float* w_Wp = P.in[28]; const float* w_bp = P.in[29];
  const float* w_We = P.in[30]; const float* w_be = P.in[31];
  const float* w_Wa = P.in[32]; const float* w_ba = P.in[33];
  float* out = P.out;

  // ------- global scratch -------
  float* ws    = P.ws;
  float* harr  = ws;                  // 1024
  float* keyw  = ws + 1024;           // 256
  float* keyr  = ws + 1280;           // 256
  float* ersv  = ws + 1536;           // 256
  float* addv  = ws + 1792;           // 256
  float* scal  = ws + 2048;           // 16
  float* P0    = ws + 2064;           // 4096
  float* P1    = ws + 6160;           // 4096 (ends 10256)
  unsigned long long* u64b = (unsigned long long*)(ws + 10256);
  unsigned long long* pubA0 = u64b;                   // 128*PUBSTR
  unsigned long long* pubA1 = pubA0 + 128*PUBSTR;     // 128*PUBSTR
  unsigned long long* wEF = pubA1 + 128*PUBSTR;       // 128 each
  unsigned long long* wPF = wEF + 128;
  unsigned long long* wEL = wPF + 128;
  unsigned long long* wPL = wEL + 128;
  unsigned long long* rEF = wPL + 128;
  unsigned long long* rPF = rEF + 128;
  unsigned long long* rEL = rPF + 128;
  unsigned long long* rPL = rEL + 128;
  unsigned long long* pubArr[2] = { pubA0, pubA1 };
  float* Pbuf[2] = { P0, P1 };

  // ------- LDS -------
  __shared__ float s_mem[RPB * Dsz];   // 128KB
  __shared__ float s_xg[16 * Tlen];    // 8KB: x-part of gates
  __shared__ float s_co[Hsz];
  __shared__ float s_a[256], s_b[256], s_c[256];
  __shared__ float s_rv[256];
  __shared__ float s_norm[RPB];
  __shared__ float s_e[RPB];
  __shared__ float s_bw[RPB];
  __shared__ float s_rw[RPB];
  __shared__ float s_ww[RPB];
  __shared__ float s_red[8];
  __shared__ float s_lg[16];
  __shared__ float s_hg[16];
  __shared__ float s_wsum[8];
  __shared__ float s_w2[2];
  __shared__ float s_cst[4];
  __shared__ float s_bd[4];
  __shared__ float s_scal[16];
  __shared__ float s_nk2r;
  __shared__ float s_pub;
  __shared__ float s_gval;

  unsigned int ep = 1;

  auto gbar = [&](float val, bool sum, bool fullDrain)->float{
    unsigned long long* pub = pubArr[ep & 1];
    if (fullDrain) __syncthreads(); else lbar();
    if (tid == 0)
      gstore64(&pub[(size_t)b * PUBSTR],
               ((unsigned long long)ep << 32) | (unsigned long long)__float_as_uint(val));
    if (wv == 0){
      const unsigned long long* p0 = &pub[(size_t)ln * PUBSTR];
      const unsigned long long* p1 = &pub[(size_t)(64 + ln) * PUBSTR];
      unsigned long long k0, k1;
      for (;;){
        k0 = gload64(p0); k1 = gload64(p1);
        bool ok = ((int)((unsigned)(k0 >> 32) - ep) >= 0) &&
                  ((int)((unsigned)(k1 >> 32) - ep) >= 0);
        if (__all(ok)) break;
      }
      if (sum){
        float acc = __uint_as_float((unsigned)k0) + __uint_as_float((unsigned)k1);
        acc = wred64(acc);
        if (ln == 0) s_gval = acc;
      }
    }
    lbar();
    ++ep;
    return s_gval;
  };

  auto bred512 = [&](float v)->float{
    v = wred64(v);
    lbar();
    if (ln == 0) s_red[wv] = v;
    lbar();
    return s_red[0] + s_red[1] + s_red[2] + s_red[3]
         + s_red[4] + s_red[5] + s_red[6] + s_red[7];
  };

  // shift + sharpen; scal from LDS; boundaries from s_bd; partial -> s_pub
  auto shiftSharpen = [&](int si, float* s_prevw, float S){
    float g     = sigm(s_scal[si + 1]);
    float gamma = softplusf(s_scal[si + 2]) + 1.f;
    float a0 = s_scal[si + 3], a1 = s_scal[si + 4], a2 = s_scal[si + 5];
    float mx = fmaxf(a0, fmaxf(a1, a2));
    float e0 = __expf(a0 - mx), e1 = __expf(a1 - mx), e2 = __expf(a2 - mx);
    float idn = 1.f / (e0 + e1 + e2);
    float s0 = e0 * idn, s1 = e1 * idn, s2 = e2 * idn;
    float invS = 1.f / S;
    float w = 0.f;
    if (tid < RPB){
      float gc = g * invS, gp = 1.f - g;
      float em = s_e[tid],  pm = s_prevw[tid];
      float e1n = (tid < RPB-1) ? s_e[tid+1]     : s_bd[0];
      float p1n = (tid < RPB-1) ? s_prevw[tid+1] : s_bd[1];
      float e2n = (tid > 0)     ? s_e[tid-1]     : s_bd[2];
      float p2n = (tid > 0)     ? s_prevw[tid-1] : s_bd[3];
      float gwm = gc * em  + gp * pm;
      float gw1 = gc * e1n + gp * p1n;
      float gw2 = gc * e2n + gp * p2n;
      float sh = s0 * gw1 + s1 * gwm + s2 * gw2;
      w = powf(sh, gamma);
      s_bw[tid] = w;
    }
    float tot = wred64(w);
    if (ln == 0 && wv < 2) s_w2[wv] = tot;
    lbar();
    if (tid == 0) s_pub = s_w2[0] + s_w2[1];
  };

  // ------- INIT1: zero buffers; load persistent weights -------
  {
    if (b < NG && tid < 256){ gstore(&P0[b*256 + tid], 0.f); gstore(&P1[b*256 + tid], 0.f); }
    if (b == 0){ gstore(&harr[tid], 0.f); gstore(&harr[512 + tid], 0.f); }
    if (tid < RPB){
      s_rw[tid] = read_w0[b * RPB + tid];
      s_ww[tid] = write_w0[b * RPB + tid];
    }
    if (tid < 4) s_cst[tid] = 0.f;
    if (tid < 16) s_hg[tid] = 0.f;
  }
  gbar(0.f, false, true);   // ep=1: zeroes drained & visible

  // ------- INIT-XG: precompute x-part of gates into s_xg -------
  {
    // stage inputs (128x256 floats = 128KB) into s_mem temporarily
#pragma unroll 1
    for (int i = 0; i < 16; ++i){
      int idx = i * 512 + tid;               // float4 index
      *(float4*)(&s_mem[idx * 4]) = *(const float4*)(inputs + (size_t)idx * 4);
    }
    lbar();
#pragma unroll 1
    for (int r = 0; r < 16; ++r){
      int row = (r >> 2) * Hsz + (b << 2) + (r & 3);
      if (tid < 64)
        *(float4*)(&s_c[tid * 4]) = *(const float4*)(W_ih + (size_t)row * (Isz + Dsz) + tid * 4);
      lbar();
      int t0 = tid >> 2, q = tid & 3;
      float acc = 0.f;
#pragma unroll
      for (int k = q * 64; k < q * 64 + 64; k += 4){
        float4 wv4 = *(const float4*)(&s_c[k]);
        float4 xv4 = *(const float4*)(&s_mem[t0 * 256 + k]);
        acc += wv4.x*xv4.x + wv4.y*xv4.y + wv4.z*xv4.z + wv4.w*xv4.w;
      }
      acc += __shfl_xor(acc, 1, 64);
      acc += __shfl_xor(acc, 2, 64);
      if (q == 0) s_xg[r * Tlen + t0] = acc + b_ih[row] + b_hh[row];
      lbar();
    }
  }

  // ------- INIT2: memory rows -> LDS, norms, initial rvec partials into P1 -------
  {
#pragma unroll 1
    for (int it = 0; it < 16; ++it){
      int ml = it * 8 + wv;
      int m  = b * RPB + ml;
      float4 v = *(const float4*)(mem0 + (size_t)m * Dsz + ln * 4);
      *(float4*)(&s_mem[ml * Dsz + ln * 4]) = v;
      float n2 = wred64(v.x*v.x + v.y*v.y + v.z*v.z + v.w*v.w);
      if (ln == 0) s_norm[ml] = sqrtf(n2);
    }
    lbar();
    int col = tid & 255, half = tid >> 8;
    float acc = 0.f;
#pragma unroll 1
    for (int j = half * 64; j < half * 64 + 64; ++j) acc += s_rw[j] * s_mem[j * Dsz + col];
    if (half == 0) s_a[col] = acc;
    lbar();
    if (half == 1) atomicAdd(&P1[(b & (NG-1)) * 256 + col], acc + s_a[col]);
  }
  gbar(0.f, false, true);   // ep=2: atomics drained

  float Srcarry = 1.f;

  // =================== time loop (6 barriers/step) ===================
  for (int t = 0; t < Tlen; ++t){
    float* hcur = harr + ((t + 1) & 1) * Hsz;
    float* Pcur = Pbuf[t & 1];          // J(t) writes
    float* Prd  = Pbuf[(t + 1) & 1];    // A(t) reads

    // ---- A: rvec normalize + tiny rvec-GEMV + LSTM elementwise ----
    {
      float SrDiv = (t == 0) ? 1.f : (Srcarry + 1e-8f);
      if (t > 0 && tid < RPB) s_rw[tid] = s_bw[tid] / SrDiv;
      if (tid < 256){
        float rvv = 0.f;
#pragma unroll
        for (int p = 0; p < NG; ++p) rvv += gload(&Prd[p * 256 + tid]);
        s_rv[tid] = rvv / SrDiv;
      }
      lbar();
      int dd = tid >> 5;          // 0..15: gate = dd>>2, unit = dd&3
      int l  = tid & 31;
      int row = (dd >> 2) * Hsz + (b << 2) + (dd & 3);
      const float* wi = W_ih + (size_t)row * (Isz + Dsz) + Isz;  // rvec columns
      int k = l * 8;
      float4 a0 = *(const float4*)(wi + k);
      float4 a1 = *(const float4*)(wi + k + 4);
      float4 r0 = *(const float4*)(&s_rv[k]);
      float4 r1 = *(const float4*)(&s_rv[k + 4]);
      float acc = a0.x*r0.x + a0.y*r0.y + a0.z*r0.z + a0.w*r0.w
                + a1.x*r1.x + a1.y*r1.y + a1.z*r1.z + a1.w*r1.w;
      acc = wred32(acc);
      if (l == 0) s_lg[dd] = acc + s_xg[dd * Tlen + t] + s_hg[dd];
      lbar();
      if (tid < 4){
        int j = (b << 2) + tid;
        float iv = s_lg[tid], fv = s_lg[4 + tid], gv = s_lg[8 + tid], ov = s_lg[12 + tid];
        float cn = sigm(fv) * s_cst[tid] + sigm(iv) * tanhf(gv);
        s_cst[tid] = cn;
        gstore(&hcur[j], sigm(ov) * tanhf(cn));
      }
    }
    gbar(0.f, false, true);   // h drained

    // ---- C: head projections + output GEMV (balanced) ----
    {
      s_co[tid] = gload(&hcur[tid]);
      lbar();
#pragma unroll
      for (int qi = 0; qi < 2; ++qi){
        int q = qi * 8 + wv;          // 0..15
        int slot = q * 128 + b;
        if (q < 11 && slot < 1292){
          const float* Wrow = nullptr; float bias = 0.f; int len = 512;
          float* dst = nullptr; bool act = false; bool plain = false;
          if (slot < 256){ Wrow = w_Wk + (size_t)slot * Hsz; bias = w_bk[slot]; dst = keyw + slot; }
          else if (slot < 512){ int i = slot - 256; Wrow = w_We + (size_t)i * Hsz; bias = w_be[i]; dst = ersv + i; act = true; }
          else if (slot < 768){ int i = slot - 512; Wrow = w_Wa + (size_t)i * Hsz; bias = w_ba[i]; dst = addv + i; }
          else if (slot < 1024){ int i = slot - 768; Wrow = r_Wk + (size_t)i * Hsz; bias = r_bk[i]; dst = keyr + i; }
          else if (slot < 1280){ int i = slot - 1024; Wrow = Wo + (size_t)i * (Hsz + Dsz); bias = bo[i]; len = 768; dst = out + (size_t)t * Isz + i; plain = true; }
          else {
            int i = slot - 1280;
            int ii = (i >= 6) ? i - 6 : i;
            bool rh = (i >= 6);
            const float *Wt, *bt; int row = 0;
            if (ii == 0){ Wt = rh ? r_Wb : w_Wb; bt = rh ? r_bb : w_bb; }
            else if (ii == 1){ Wt = rh ? r_Wg : w_Wg; bt = rh ? r_bg : w_bg; }
            else if (ii == 2){ Wt = rh ? r_Wp : w_Wp; bt = rh ? r_bp : w_bp; }
            else { Wt = rh ? r_Ws : w_Ws; bt = rh ? r_bs : w_bs; row = ii - 3; }
            Wrow = Wt + (size_t)row * Hsz; bias = bt[row]; dst = scal + i;
          }
          float acc = 0.f;
          if (len == 512){
            int k = ln * 8;
            float4 a0 = *(const float4*)(Wrow + k);
            float4 a1 = *(const float4*)(Wrow + k + 4);
            float4 c0 = *(const float4*)(&s_co[k]);
            float4 c1 = *(const float4*)(&s_co[k + 4]);
            acc = a0.x*c0.x + a0.y*c0.y + a0.z*c0.z + a0.w*c0.w
                + a1.x*c1.x + a1.y*c1.y + a1.z*c1.z + a1.w*c1.w;
          } else {
#pragma unroll 1
            for (int kk = ln; kk < 768; kk += 64){
              float xv = (kk < Hsz) ? s_co[kk] : s_rv[kk - Hsz];
              acc += Wrow[kk] * xv;
            }
          }
          acc = wred64(acc);
          if (ln == 0){
            float v = acc + bias;
            if (act) v = sigm(v);
            if (plain) *dst = v; else gstore(dst, v);
          }
        }
      }
    }
    gbar(0.f, false, true);   // projections drained

    // ---- D: write-head content scores; prefetch scal; tagged boundary pubs ----
    float S_w;
    {
      float* Pnx = Pbuf[(t + 1) & 1];
      if (b < NG && tid < 256) gstore(&Pnx[b * 256 + tid], 0.f);
      if (wv == 7 && ln < 16) s_scal[ln] = gload(&scal[ln]);
      if (tid < 256) s_a[tid] = gload(&keyw[tid]);
      float nk2 = bred512((tid < 256) ? s_a[tid] * s_a[tid] : 0.f);
      float beta  = softplusf(gload(&scal[0]));
      float invbk = beta / fmaxf(sqrtf(nk2), 1e-12f);
      float esum = 0.f;
#pragma unroll 1
      for (int it = 0; it < 16; ++it){
        int ml = it * 8 + wv;
        float4 v  = *(const float4*)(&s_mem[ml * Dsz + ln * 4]);
        float4 kv = *(const float4*)(&s_a[ln * 4]);
        float d = wred64(v.x*kv.x + v.y*kv.y + v.z*kv.z + v.w*kv.w);
        float score = d * invbk / fmaxf(s_norm[ml], 1e-12f);
        float e = __expf(score - beta);
        if (ln == 0){ s_e[ml] = e; esum += e; }
      }
      if (ln == 0) s_wsum[wv] = esum;
      lbar();
      if (tid == 0){
        float tot = 0.f;
#pragma unroll
        for (int k = 0; k < 8; ++k) tot += s_wsum[k];
        s_pub = tot;
        unsigned long long tg = ((unsigned long long)ep << 32);
        gstore64(&wEF[b], tg | (unsigned long long)__float_as_uint(s_e[0]));
        gstore64(&wPF[b], tg | (unsigned long long)__float_as_uint(s_ww[0]));
        gstore64(&wEL[b], tg | (unsigned long long)__float_as_uint(s_e[RPB-1]));
        gstore64(&wPL[b], tg | (unsigned long long)__float_as_uint(s_ww[RPB-1]));
      }
      S_w = gbar(s_pub, true, false);
    }

    // ---- F: boundary wait / H-input prefetch / W_hh*h GEMV / shift+sharpen ----
    float Sw;
    {
      unsigned want = ep - 1;
      if (wv == 0 && ln < 4){
        unsigned long long* bp = (ln == 0) ? &wEF[(b + 1) & (NBLK-1)]
                               : (ln == 1) ? &wPF[(b + 1) & (NBLK-1)]
                               : (ln == 2) ? &wEL[(b - 1) & (NBLK-1)]
                                           : &wPL[(b - 1) & (NBLK-1)];
        unsigned long long k;
        do { k = gload64(bp); } while ((int)((unsigned)(k >> 32) - want) < 0);
        s_bd[ln] = __uint_as_float((unsigned)k);
      } else if (wv >= 4){
        int i = tid - 256;
        s_a[i] = gload(&ersv[i]); s_b[i] = gload(&addv[i]); s_c[i] = gload(&keyr[i]);
      } else if (wv == 2 || wv == 3){
        // hg = W_hh * h(t)  (s_co persists from C)
        int qq = tid - 128;            // 0..127
        int rr = qq >> 3, sub = qq & 7;
        int row = (rr >> 2) * Hsz + (b << 2) + (rr & 3);
        const float* wh = W_hh + (size_t)row * Hsz + sub * 64;
        const float* hc = &s_co[sub * 64];
        float acc = 0.f;
#pragma unroll
        for (int i = 0; i < 64; i += 4){
          float4 w4 = *(const float4*)(wh + i);
          float4 h4 = *(const float4*)(hc + i);
          acc += w4.x*h4.x + w4.y*h4.y + w4.z*h4.z + w4.w*h4.w;
        }
        acc += __shfl_xor(acc, 1, 64);
        acc += __shfl_xor(acc, 2, 64);
        acc += __shfl_xor(acc, 4, 64);
        if (sub == 0) s_hg[rr] = acc;
      }
      lbar();
      if (wv == 4){   // read-key norm for H
        float v = 0.f;
#pragma unroll
        for (int i = 0; i < 4; ++i){ float c = s_c[ln * 4 + i]; v += c * c; }
        v = wred64(v);
        if (ln == 0) s_nk2r = v;
      }
      shiftSharpen(0, s_ww, S_w);
      Sw = gbar(s_pub, true, false);
    }

    // ---- H: normalize ww, memory update, new norms + read scores ----
    float S_r;
    {
      float beta  = softplusf(s_scal[6]);
      float invbk = beta / fmaxf(sqrtf(s_nk2r), 1e-12f);
      float invSw = 1.f / (Sw + 1e-8f);
      if (tid < RPB) s_ww[tid] = s_bw[tid] * invSw;
      float esum = 0.f;
#pragma unroll 1
      for (int it = 0; it < 16; ++it){
        int ml = it * 8 + wv;
        float wwm = s_bw[ml] * invSw;
        int off = ml * Dsz + ln * 4;
        float4 mv = *(const float4*)(&s_mem[off]);
        float4 er = *(const float4*)(&s_a[ln * 4]);
        float4 ad = *(const float4*)(&s_b[ln * 4]);
        float4 kr = *(const float4*)(&s_c[ln * 4]);
        float4 nv;
        nv.x = mv.x * (1.f - wwm * er.x) + wwm * ad.x;
        nv.y = mv.y * (1.f - wwm * er.y) + wwm * ad.y;
        nv.z = mv.z * (1.f - wwm * er.z) + wwm * ad.z;
        nv.w = mv.w * (1.f - wwm * er.w) + wwm * ad.w;
        *(float4*)(&s_mem[off]) = nv;
        float n2 = nv.x*nv.x + nv.y*nv.y + nv.z*nv.z + nv.w*nv.w;
        float dt = nv.x*kr.x + nv.y*kr.y + nv.z*kr.z + nv.w*kr.w;
        n2 = wred64(n2);
        dt = wred64(dt);
        float nr = sqrtf(n2);
        if (ln == 0) s_norm[ml] = nr;
        float score = dt * invbk / fmaxf(nr, 1e-12f);
        float e = __expf(score - beta);
        if (ln == 0){ s_e[ml] = e; esum += e; }
      }
      if (ln == 0) s_wsum[wv] = esum;
      lbar();
      if (tid == 0){
        float tot = 0.f;
#pragma unroll
        for (int k = 0; k < 8; ++k) tot += s_wsum[k];
        s_pub = tot;
        unsigned long long tg = ((unsigned long long)ep << 32);
        gstore64(&rEF[b], tg | (unsigned long long)__float_as_uint(s_e[0]));
        gstore64(&rPF[b], tg | (unsigned long long)__float_as_uint(s_rw[0]));
        gstore64(&rEL[b], tg | (unsigned long long)__float_as_uint(s_e[RPB-1]));
        gstore64(&rPL[b], tg | (unsigned long long)__float_as_uint(s_rw[RPB-1]));
      }
      S_r = gbar(s_pub, true, false);
    }

    // ---- J: read-head shift+sharpen; UNNORMALIZED rvec partials ----
    {
      unsigned want = ep - 1;
      if (wv == 0 && ln < 4){
        unsigned long long* bp = (ln == 0) ? &rEF[(b + 1) & (NBLK-1)]
                               : (ln == 1) ? &rPF[(b + 1) & (NBLK-1)]
                               : (ln == 2) ? &rEL[(b - 1) & (NBLK-1)]
                                           : &rPL[(b - 1) & (NBLK-1)];
        unsigned long long k;
        do { k = gload64(bp); } while ((int)((unsigned)(k >> 32) - want) < 0);
        s_bd[ln] = __uint_as_float((unsigned)k);
      }
      lbar();
      shiftSharpen(6, s_rw, S_r);
      lbar();
      int col = tid & 255, half = tid >> 8;
      float acc = 0.f;
#pragma unroll 1
      for (int j = half * 64; j < half * 64 + 64; ++j) acc += s_bw[j] * s_mem[j * Dsz + col];
      if (half == 0) s_a[col] = acc;
      lbar();
      if (half == 1) atomicAdd(&Pcur[(b & (NG-1)) * 256 + col], acc + s_a[col]);
      Srcarry = gbar(s_pub, true, true);   // full drain: atomics before pub
    }
  }
}

extern "C" void kernel_launch(void* const* d_in, const int* in_sizes, int n_in,
                              void* d_out, int out_size, void* d_ws, size_t ws_size,
                              hipStream_t stream)
{
  (void)in_sizes; (void)out_size;
  if (n_in < 34) return;
  if (ws_size < (size_t)98304) return;   // ~82KB scratch needed
  Params P;
  for (int i = 0; i < 34; ++i) P.in[i] = (const float*)d_in[i];
  P.out = (float*)d_out;
  P.ws  = (float*)d_ws;
  hipLaunchKernelGGL(ntm_kernel, dim3(NBLK), dim3(NTHR), 0, stream, P);
}